// Round 12
// baseline (397.366 us; speedup 1.0000x reference)
//
#include <hip/hip_runtime.h>

#define BB 16
#define KK 2048
#define NPROPN 256
#define NS 16
#define CSEED 256
#define CMLP 128
#define CIN 259
#define OUTCH 119
#define KZZ 1024

// output offsets in floats (concatenated tuple order)
#define O0  0UL
#define O1  8192UL
#define O2  20480UL
#define O3  69632UL
#define O4  118784UL
#define O5  192512UL
#define O6  413696UL
#define O7  487424UL
#define O8  585728UL
#define O9  4780032UL
#define O10 4829184UL
#define O11 4902912UL

// ws layout (floats)
#define WS_NEWXYZ 0
#define WS_W0T 12288
#define WS_W1T 45440
#define WS_W2T 61824
#define WS_C1T 78208
#define WS_C2T 94592
#define WS_C3T 110976
#define WS_FEATT 131072UL
#define WS_NEED_BYTES ((size_t)(WS_FEATT + (size_t)BB * KK * CSEED) * 4)

#define XROWS 131
#define XSTR (XROWS * 16)  // 2096 floats per wave buffer

// DPP argmax-reduce step on packed key (hi=dist bits (>=0), lo=~idx) — R5-proven
#define RSTEP(CTRL)                                                                          \
  {                                                                                          \
    unsigned shi = (unsigned)__builtin_amdgcn_update_dpp((int)hi, (int)hi, (CTRL), 0xF, 0xF, false); \
    unsigned slo = (unsigned)__builtin_amdgcn_update_dpp((int)lo, (int)lo, (CTRL), 0xF, 0xF, false); \
    bool gt = (shi > hi) || ((shi == hi) && (slo > lo));                                     \
    hi = gt ? shi : hi;                                                                      \
    lo = gt ? slo : lo;                                                                      \
  }

__device__ __forceinline__ void fma4(float4& a, float s, const float4& w) {
  a.x = fmaf(s, w.x, a.x); a.y = fmaf(s, w.y, a.y);
  a.z = fmaf(s, w.z, a.z); a.w = fmaf(s, w.w, a.w);
}
__device__ __forceinline__ float fget(const float4& v, int r) {
  return r == 0 ? v.x : (r == 1 ? v.y : (r == 2 ? v.z : v.w));
}
// swizzled LDS addr: element (row, s4) at row*16 + ((s4 ^ (row>>2)&3)<<2)
__device__ __forceinline__ int xadr(int row, int s4) {
  return row * 16 + (((s4) ^ ((row >> 2) & 3)) << 2);
}

template<bool TR>
__global__ __launch_bounds__(256) void prep_kernel(
    const float* __restrict__ xyz, const float* __restrict__ vote_feat,
    const float* __restrict__ w0, const float* __restrict__ w1, const float* __restrict__ w2,
    const float* __restrict__ c1w, const float* __restrict__ c2w, const float* __restrict__ c3w,
    const float* __restrict__ pz, const float* __restrict__ cz,
    const float* __restrict__ pxy, const float* __restrict__ cxy,
    const float* __restrict__ pl, const float* __restrict__ cl,
    const float* __restrict__ az, const float* __restrict__ axy,
    float* __restrict__ wsf, float* __restrict__ out) {
  constexpr int FPS_END = 16;
  constexpr int FEATT_END = FPS_END + (TR ? 1024 : 0);
  constexpr int TRW_END = FEATT_END + 450;
  constexpr int SURF_END = TRW_END + 192;

  const int bid = blockIdx.x;
  const int t = threadIdx.x;
  __shared__ float smem[8448];  // FPS: sxyz 6144 + nxb 768 ; transpose: [32][260] tile
  __shared__ __align__(16) float wvv[2][4];
  __shared__ __align__(16) int wii[2][4];

  if (bid < FPS_END) {
    // ---- FPS (R5-exact): 4 waves, 1 barrier/iter, new_xyz buffered in LDS ----
    const int b = bid;
    const float* p = xyz + (size_t)b * KK * 3;
    float* sxyz = smem;
    float* nxb = smem + 6144;
    const int lane = t & 63, w = t >> 6;
    float pxr[8], pyr[8], pzr[8], dd[8];
#pragma unroll
    for (int j = 0; j < 8; ++j) {
      int i = j * 256 + t;
      float x = p[i * 3 + 0], y = p[i * 3 + 1], z = p[i * 3 + 2];
      pxr[j] = x; pyr[j] = y; pzr[j] = z; dd[j] = 1e10f;
      sxyz[i * 3 + 0] = x; sxyz[i * 3 + 1] = y; sxyz[i * 3 + 2] = z;
    }
    __syncthreads();
    int cur = 0;
    for (int it = 0; it < NPROPN; ++it) {
      const int pb = it & 1;
      float cx = sxyz[cur * 3 + 0];
      float cy = sxyz[cur * 3 + 1];
      float cz2 = sxyz[cur * 3 + 2];
      if (t == 0) { nxb[it * 3 + 0] = cx; nxb[it * 3 + 1] = cy; nxb[it * 3 + 2] = cz2; }
      float best = -1.0f;
      int bidx = 0;
#pragma unroll
      for (int j = 0; j < 8; ++j) {
        float dx = __fsub_rn(pxr[j], cx);
        float dy = __fsub_rn(pyr[j], cy);
        float dz = __fsub_rn(pzr[j], cz2);
        float d = __fadd_rn(__fadd_rn(__fmul_rn(dx, dx), __fmul_rn(dy, dy)), __fmul_rn(dz, dz));
        float nd = fminf(dd[j], d);
        dd[j] = nd;
        if (nd > best) { best = nd; bidx = j * 256 + t; }  // strict >: first-index per lane
      }
      unsigned hi = __float_as_uint(best);
      unsigned lo = ~(unsigned)bidx;  // max(~idx) == min(idx) on dist ties
      RSTEP(0x111) RSTEP(0x112) RSTEP(0x114) RSTEP(0x118)  // row_shr 1,2,4,8
      RSTEP(0x142) RSTEP(0x143)                            // row_bcast15, row_bcast31
      if (lane == 63) { wvv[pb][w] = __uint_as_float(hi); wii[pb][w] = (int)lo; }
      __syncthreads();
      unsigned vh = __float_as_uint(wvv[pb][0]);
      unsigned vl = (unsigned)wii[pb][0];
#pragma unroll
      for (int q2 = 1; q2 < 4; ++q2) {
        unsigned ah = __float_as_uint(wvv[pb][q2]);
        unsigned al = (unsigned)wii[pb][q2];
        bool gt = (ah > vh) || ((ah == vh) && (al > vl));
        vh = gt ? ah : vh; vl = gt ? al : vl;
      }
      cur = (int)~vl;  // uniform across block
    }
    __syncthreads();
    float* nxw = wsf + WS_NEWXYZ + (size_t)b * NPROPN * 3;
    for (int i = t; i < NPROPN * 3; i += 256) nxw[i] = nxb[i];
    return;
  }

  if (TR && bid < FEATT_END) {
    // ---- vote_features transpose: [C][K] -> featT[b][k][C] ----
    int q = bid - FPS_END;
    int b = q >> 6, ck = q & 63;
    int k0 = ck << 5;
    float* tile = smem;  // [32][260]
    const float* src = vote_feat + ((size_t)b * CSEED + t) * KK + k0;
    float4 v[8];
#pragma unroll
    for (int j = 0; j < 8; ++j) v[j] = *(const float4*)(src + j * 4);
#pragma unroll
    for (int j = 0; j < 8; ++j) {
      tile[(j * 4 + 0) * 260 + t] = v[j].x;
      tile[(j * 4 + 1) * 260 + t] = v[j].y;
      tile[(j * 4 + 2) * 260 + t] = v[j].z;
      tile[(j * 4 + 3) * 260 + t] = v[j].w;
    }
    __syncthreads();
    float* dst = wsf + WS_FEATT + ((size_t)b * KK + k0) * CSEED;
    const int kk = t >> 3, cbase = (t & 7) << 2;
#pragma unroll
    for (int j = 0; j < 8; ++j) {
      int c = cbase + (j << 5);
      float4 u = make_float4(tile[kk * 260 + c], tile[kk * 260 + c + 1],
                             tile[kk * 260 + c + 2], tile[kk * 260 + c + 3]);
      *(float4*)(dst + (size_t)kk * CSEED + c) = u;
    }
    return;
  }

  if (bid < TRW_END) {
    // ---- weight transpose into ws ----
    int row = (bid - FEATT_END) * 2 + (t >> 7);
    int o = t & 127;
    if (row < 899) {
      float v; float* dst;
      if (row < 259)      { dst = wsf + WS_W0T + (size_t)row * 128; v = w0[(size_t)o * CIN + row]; }
      else if (row < 387) { int k = row - 259; dst = wsf + WS_W1T + (size_t)k * 128; v = w1[(size_t)o * 128 + k]; }
      else if (row < 515) { int k = row - 387; dst = wsf + WS_W2T + (size_t)k * 128; v = w2[(size_t)o * 128 + k]; }
      else if (row < 643) { int k = row - 515; dst = wsf + WS_C1T + (size_t)k * 128; v = c1w[(size_t)o * 128 + k]; }
      else if (row < 771) { int k = row - 643; dst = wsf + WS_C2T + (size_t)k * 128; v = c2w[(size_t)o * 128 + k]; }
      else                { int k = row - 771; dst = wsf + WS_C3T + (size_t)k * 128; v = (o < OUTCH) ? c3w[(size_t)o * 128 + k] : 0.f; }
      dst[o] = v;
    }
    return;
  }

  if (bid < SURF_END) {
    // ---- surface center selection ----
    int i = (bid - TRW_END) * 256 + t;
    int src = i / (BB * KZZ);
    int rem = i % (BB * KZZ);
    int b = rem / KZZ, k = rem % KZZ;
    const float* ps = (src == 0) ? pz : ((src == 1) ? pxy : pl);
    const float* pc = (src == 0) ? cz : ((src == 1) ? cxy : cl);
    float x0 = ps[((size_t)b * 2 + 0) * KZZ + k];
    float x1 = ps[((size_t)b * 2 + 1) * KZZ + k];
    float add = (x1 <= x0) ? 10.0f : 0.0f;
    size_t dst;
    if (src == 0)      dst = O7 + ((size_t)b * 2048 + k) * 3;
    else if (src == 1) dst = O7 + ((size_t)b * 2048 + 1024 + k) * 3;
    else               dst = O9 + ((size_t)b * KZZ + k) * 3;
    const float* c3 = pc + ((size_t)b * KZZ + k) * 3;
    out[dst + 0] = c3[0] + add;
    out[dst + 1] = c3[1] + add;
    out[dst + 2] = c3[2] + add;
    return;
  }

  {
    // ---- aggregated feature concat copy ----
    int i = (bid - SURF_END) * 256 + t;
    int q = i & 511;
    int bc = i >> 9;
    int half = q >> 8, k4 = q & 255;
    const float4* src = (const float4*)((half == 0) ? az : axy);
    float4 v = src[(size_t)bc * 256 + k4];
    float4* dst = (float4*)(out + O8);
    dst[(size_t)bc * 512 + q] = v;
  }
}

// MLP K-loop: X rows broadcast from LDS (uniform addr), W rolling float4 global loads
__device__ __forceinline__ void mlp_accum(const float* __restrict__ WT, int og, int sh,
                                          const float* __restrict__ xb, int K, float4* acc) {
  const float4* wp = (const float4*)WT + og;
  const int s4a = sh * 2, s4b = sh * 2 + 1;
#pragma unroll 4
  for (int k = 0; k < K; ++k) {
    float4 xa = *(const float4*)(xb + xadr(k, s4a));
    float4 xq = *(const float4*)(xb + xadr(k, s4b));
    float4 wv = wp[(size_t)k * 32];
    fma4(acc[0], xa.x, wv); fma4(acc[1], xa.y, wv);
    fma4(acc[2], xa.z, wv); fma4(acc[3], xa.w, wv);
    fma4(acc[4], xq.x, wv); fma4(acc[5], xq.y, wv);
    fma4(acc[6], xq.z, wv); fma4(acc[7], xq.w, wv);
  }
}

__device__ __forceinline__ void mlp_storeh(const float* __restrict__ scv, const float* __restrict__ bbv,
                                           int og, int sh, float* __restrict__ xb,
                                           const float4* __restrict__ acc) {
  float4 s4v = *(const float4*)(scv + (og << 2));
  float4 b4v = *(const float4*)(bbv + (og << 2));
#pragma unroll
  for (int r = 0; r < 4; ++r) {
    float ss = fget(s4v, r), bv = fget(b4v, r);
    float4 lo, hi;
    lo.x = fmaf(fget(acc[0], r), ss, bv); lo.x = lo.x > 0.f ? lo.x : 0.f;
    lo.y = fmaf(fget(acc[1], r), ss, bv); lo.y = lo.y > 0.f ? lo.y : 0.f;
    lo.z = fmaf(fget(acc[2], r), ss, bv); lo.z = lo.z > 0.f ? lo.z : 0.f;
    lo.w = fmaf(fget(acc[3], r), ss, bv); lo.w = lo.w > 0.f ? lo.w : 0.f;
    hi.x = fmaf(fget(acc[4], r), ss, bv); hi.x = hi.x > 0.f ? hi.x : 0.f;
    hi.y = fmaf(fget(acc[5], r), ss, bv); hi.y = hi.y > 0.f ? hi.y : 0.f;
    hi.z = fmaf(fget(acc[6], r), ss, bv); hi.z = hi.z > 0.f ? hi.z : 0.f;
    hi.w = fmaf(fget(acc[7], r), ss, bv); hi.w = hi.w > 0.f ? hi.w : 0.f;
    int row = (og << 2) + r;
    *(float4*)(xb + xadr(row, sh * 2)) = lo;
    *(float4*)(xb + xadr(row, sh * 2 + 1)) = hi;
  }
}

// ONE WAVE per block: all state wave-private, no __syncthreads anywhere.
// LDS ~8.5 KB/block -> ~18 blocks/CU (vs 4x-wave packing at 16 waves/CU).
template<bool TR>
__global__ __launch_bounds__(64) void proposal_kernel(
    const float* __restrict__ vote_xyz, const float* __restrict__ vote_feat,
    const float* __restrict__ wsf, const float* __restrict__ msa,
    const float* __restrict__ s0, const float* __restrict__ b0,
    const float* __restrict__ s1, const float* __restrict__ b1,
    const float* __restrict__ s2, const float* __restrict__ b2,
    const float* __restrict__ c1b, const float* __restrict__ bn1s, const float* __restrict__ bn1b,
    const float* __restrict__ c2b, const float* __restrict__ bn2s, const float* __restrict__ bn2b,
    const float* __restrict__ c3b,
    float* __restrict__ out) {
  __shared__ __align__(16) float Xw[XSTR];  // 131-row chunk / H buffer / epilogue scratch
  __shared__ int sel_s[NS];
  __shared__ float sc_s[3], sh_s[3];
  __shared__ int scls_s;

  const int l = threadIdx.x;                 // 0..63
  const int b = blockIdx.x >> 8;
  const int pp = blockIdx.x & 255;
  const int sh = l >> 5, og = l & 31;
  // epilogue overlays into Xw (dead after MLP; wave-private in-order DS)
  float* feat_p = Xw;          // 128
  float* n1_p   = Xw + 128;    // 128
  float* n2_p   = Xw + 256;    // 128
  float* ntv_p  = Xw + 384;    // 119 (pad to 120)

  const float* nx = wsf + WS_NEWXYZ + ((size_t)b * NPROPN + pp) * 3;
  const float cx = nx[0], cy = nx[1], cz = nx[2];
  const float* px = vote_xyz + (size_t)b * KK * 3;
  const float RR = 0.09000000357627869f;  // f32(0.3f*0.3f)

  // ---- ball query: first <=16 in-radius indices, ascending; batched loads ----
  {
    int total = 0;
    for (int j0 = 0; j0 < 32 && total < NS; j0 += 8) {
      float dq[8];
#pragma unroll
      for (int jj = 0; jj < 8; ++jj) {
        int i = ((j0 + jj) << 6) + l;
        float dx = __fsub_rn(px[i * 3 + 0], cx);
        float dy = __fsub_rn(px[i * 3 + 1], cy);
        float dz = __fsub_rn(px[i * 3 + 2], cz);
        dq[jj] = __fadd_rn(__fadd_rn(__fmul_rn(dx, dx), __fmul_rn(dy, dy)), __fmul_rn(dz, dz));
      }
#pragma unroll
      for (int jj = 0; jj < 8; ++jj) {
        bool in = (dq[jj] <= RR);
        unsigned long long bal = __ballot(in);
        if (in) {
          int pos = total + __popcll(bal & ((1ull << l) - 1ull));
          if (pos < NS) sel_s[pos] = ((j0 + jj) << 6) + l;
        }
        total += __popcll(bal);
      }
    }
    if (l == 0 && total < NS) {
      int first = (total > 0) ? sel_s[0] : 0;
      for (int i = total; i < NS; ++i) sel_s[i] = first;
    }
    __builtin_amdgcn_wave_barrier();
  }

  // ---- gather chunk0 (global rows 0..130) + prefetch chunk1 into regs ----
  float4 pf[8];
  {
    const int s = l >> 2, q = l & 3;
    const int idx = sel_s[s];
    const int s4 = s >> 2, se = s & 3;
    if (q < 3) {
      float pv = px[idx * 3 + q];
      float cv = (q == 0) ? cx : ((q == 1) ? cy : cz);
      Xw[xadr(q, s4) + se] = __fdiv_rn(__fsub_rn(pv, cv), 0.3f);
    }
    if constexpr (TR) {
      const float* fr = wsf + WS_FEATT + ((size_t)b * KK + idx) * CSEED;
#pragma unroll
      for (int m = 0; m < 8; ++m) {
        int c = (m << 4) + (q << 2);
        float4 v = *(const float4*)(fr + c);
        Xw[xadr(3 + c + 0, s4) + se] = v.x;
        Xw[xadr(3 + c + 1, s4) + se] = v.y;
        Xw[xadr(3 + c + 2, s4) + se] = v.z;
        Xw[xadr(3 + c + 3, s4) + se] = v.w;
      }
#pragma unroll
      for (int m = 0; m < 8; ++m) pf[m] = *(const float4*)(fr + 128 + (m << 4) + (q << 2));
    } else {
      const float* fb = vote_feat + (size_t)b * CSEED * KK + idx;
#pragma unroll
      for (int m = 0; m < 8; ++m) {
        int c = (m << 4) + (q << 2);
        Xw[xadr(3 + c + 0, s4) + se] = fb[(size_t)(c + 0) * KK];
        Xw[xadr(3 + c + 1, s4) + se] = fb[(size_t)(c + 1) * KK];
        Xw[xadr(3 + c + 2, s4) + se] = fb[(size_t)(c + 2) * KK];
        Xw[xadr(3 + c + 3, s4) + se] = fb[(size_t)(c + 3) * KK];
      }
#pragma unroll
      for (int m = 0; m < 8; ++m) {
        int c = 128 + (m << 4) + (q << 2);
        pf[m].x = fb[(size_t)(c + 0) * KK];
        pf[m].y = fb[(size_t)(c + 1) * KK];
        pf[m].z = fb[(size_t)(c + 2) * KK];
        pf[m].w = fb[(size_t)(c + 3) * KK];
      }
    }
    __builtin_amdgcn_wave_barrier();
  }

  float4 acc[8];
#pragma unroll
  for (int i = 0; i < 8; ++i) acc[i] = make_float4(0.f, 0.f, 0.f, 0.f);

  // ---- L0 part1: buffer rows 0..130 (global k 0..130) ----
  mlp_accum(wsf + WS_W0T, og, sh, Xw, 131, acc);
  __builtin_amdgcn_wave_barrier();

  // ---- overwrite buffer rows 0..127 with chunk1 (global k 131..258) ----
  {
    const int s = l >> 2, q = l & 3;
    const int s4 = s >> 2, se = s & 3;
#pragma unroll
    for (int m = 0; m < 8; ++m) {
      int c = (m << 4) + (q << 2);
      Xw[xadr(c + 0, s4) + se] = pf[m].x;
      Xw[xadr(c + 1, s4) + se] = pf[m].y;
      Xw[xadr(c + 2, s4) + se] = pf[m].z;
      Xw[xadr(c + 3, s4) + se] = pf[m].w;
    }
    __builtin_amdgcn_wave_barrier();
  }

  // ---- L0 part2 + scale/bias/relu -> H1 (rows 0..127) ----
  mlp_accum(wsf + WS_W0T + 131 * 128, og, sh, Xw, 128, acc);
  mlp_storeh(s0, b0, og, sh, Xw, acc);
  __builtin_amdgcn_wave_barrier();

  // ---- L1 ----
#pragma unroll
  for (int i = 0; i < 8; ++i) acc[i] = make_float4(0.f, 0.f, 0.f, 0.f);
  mlp_accum(wsf + WS_W1T, og, sh, Xw, 128, acc);
  mlp_storeh(s1, b1, og, sh, Xw, acc);
  __builtin_amdgcn_wave_barrier();

  // ---- L2 ----
#pragma unroll
  for (int i = 0; i < 8; ++i) acc[i] = make_float4(0.f, 0.f, 0.f, 0.f);
  mlp_accum(wsf + WS_W2T, og, sh, Xw, 128, acc);

  // ---- epilogue: scale/bias/relu + maxpool over 16 samples ----
  float mr[4];
  {
    float4 s4v = *(const float4*)(s2 + (og << 2));
    float4 b4v = *(const float4*)(b2 + (og << 2));
#pragma unroll
    for (int r = 0; r < 4; ++r) {
      float ss = fget(s4v, r), bv = fget(b4v, r);
      float m = 0.f;  // relu floor
#pragma unroll
      for (int i = 0; i < 8; ++i) m = fmaxf(m, fmaf(fget(acc[i], r), ss, bv));
      mr[r] = fmaxf(m, __shfl_xor(m, 32));
    }
  }
  __builtin_amdgcn_wave_barrier();  // all Xw reads (L2) done before overlay writes
  if (sh == 0) *(float4*)(feat_p + (og << 2)) = make_float4(mr[0], mr[1], mr[2], mr[3]);
  __builtin_amdgcn_wave_barrier();

  // ---- obj_surface_feature tile x6 ----
  {
    float* o11 = out + O11 + (size_t)b * CMLP * 1536;
#pragma unroll
    for (int r = 0; r < 4; ++r) {
      size_t rowb = (size_t)((og << 2) + r) * 1536 + pp;
#pragma unroll
      for (int rr2 = 0; rr2 < 3; ++rr2) {
        int rr = sh * 3 + rr2;
        o11[rowb + rr * 256] = mr[r];
      }
    }
  }

  // ---- conv chain (weights from global ws, coalesced) ----
  {
    const float* C1T = wsf + WS_C1T;
    float a0 = 0.f, a1 = 0.f;
#pragma unroll 4
    for (int k = 0; k < CMLP; ++k) {
      float f = feat_p[k];
      float2 wv = *(const float2*)(C1T + (size_t)k * 128 + (l << 1));
      a0 = fmaf(f, wv.x, a0); a1 = fmaf(f, wv.y, a1);
    }
    int o0 = l << 1, o1 = o0 + 1;
    float v0 = fmaf(a0 + c1b[o0], bn1s[o0], bn1b[o0]); v0 = v0 > 0.f ? v0 : 0.f;
    float v1 = fmaf(a1 + c1b[o1], bn1s[o1], bn1b[o1]); v1 = v1 > 0.f ? v1 : 0.f;
    *(float2*)(n1_p + o0) = make_float2(v0, v1);
    __builtin_amdgcn_wave_barrier();
  }
  {
    const float* C2T = wsf + WS_C2T;
    float a0 = 0.f, a1 = 0.f;
#pragma unroll 4
    for (int k = 0; k < CMLP; ++k) {
      float f = n1_p[k];
      float2 wv = *(const float2*)(C2T + (size_t)k * 128 + (l << 1));
      a0 = fmaf(f, wv.x, a0); a1 = fmaf(f, wv.y, a1);
    }
    int o0 = l << 1, o1 = o0 + 1;
    float v0 = fmaf(a0 + c2b[o0], bn2s[o0], bn2b[o0]); v0 = v0 > 0.f ? v0 : 0.f;
    float v1 = fmaf(a1 + c2b[o1], bn2s[o1], bn2b[o1]); v1 = v1 > 0.f ? v1 : 0.f;
    *(float2*)(n2_p + o0) = make_float2(v0, v1);
    __builtin_amdgcn_wave_barrier();
  }
  {
    const float* C3T = wsf + WS_C3T;
    float a0 = 0.f, a1 = 0.f;
#pragma unroll 4
    for (int k = 0; k < CMLP; ++k) {
      float f = n2_p[k];
      float2 wv = *(const float2*)(C3T + (size_t)k * 128 + (l << 1));
      a0 = fmaf(f, wv.x, a0); a1 = fmaf(f, wv.y, a1);
    }
    int o0 = l << 1, o1 = o0 + 1;
    float bb0 = (o0 < OUTCH) ? c3b[o0] : 0.f;
    float bb1 = (o1 < OUTCH) ? c3b[o1] : 0.f;
    *(float2*)(ntv_p + o0) = make_float2(a0 + bb0, a1 + bb1);
    __builtin_amdgcn_wave_barrier();
  }

  // ---- heads ----
  {
    const size_t bp = (size_t)b * NPROPN + pp;
    if (l < 2) out[O0 + bp * 2 + l] = ntv_p[l];
    if (l < 3) {
      float cv = ((l == 0) ? cx : ((l == 1) ? cy : cz)) + ntv_p[2 + l];
      sc_s[l] = cv;
      out[O1 + bp * 3 + l] = cv;
    }
    if (l < 12) {
      out[O2 + bp * 12 + l] = ntv_p[5 + l];
      out[O3 + bp * 12 + l] = ntv_p[17 + l] * 0.2617993877991494f;
    }
    if (l < 18) {
      out[O4 + bp * 18 + l] = ntv_p[29 + l];
      out[O6 + bp * 18 + l] = ntv_p[101 + l];
    }
    if (l < 54) out[O5 + bp * 54 + l] = ntv_p[47 + l] * msa[l];
    if (l == 0) {
      float bvv = ntv_p[29]; int bii = 0;
      for (int i2 = 1; i2 < 18; ++i2)
        if (ntv_p[29 + i2] > bvv) { bvv = ntv_p[29 + i2]; bii = i2; }
      scls_s = bii;
    }
    __builtin_amdgcn_wave_barrier();
    if (l < 3) {
      int cls = scls_s;
      float m = msa[cls * 3 + l];
      sh_s[l] = fmaf(ntv_p[47 + cls * 3 + l], m, m) * 0.5f;
    }
    __builtin_amdgcn_wave_barrier();
    if (l < 18) {
      const int r = l / 3, j2 = l % 3;
      const int axis[6] = {2, 2, 1, 1, 0, 0};
      float v = sc_s[j2];
      if (j2 == axis[r]) v = (r & 1) ? (v - sh_s[j2]) : (v + sh_s[j2]);
      out[O10 + (size_t)b * 4608 + (size_t)(r * 256 + pp) * 3 + j2] = v;
    }
  }
}

extern "C" void kernel_launch(void* const* d_in, const int* in_sizes, int n_in,
                              void* d_out, int out_size, void* d_ws, size_t ws_size,
                              hipStream_t stream) {
  (void)in_sizes; (void)n_in; (void)out_size;
  const float* vote_xyz = (const float*)d_in[0];
  const float* vote_feat = (const float*)d_in[1];
  const float* pz   = (const float*)d_in[2];
  const float* cz   = (const float*)d_in[3];
  const float* az   = (const float*)d_in[4];
  const float* pxy  = (const float*)d_in[5];
  const float* cxy  = (const float*)d_in[6];
  const float* axy  = (const float*)d_in[7];
  const float* pl   = (const float*)d_in[8];
  const float* cl   = (const float*)d_in[9];
  const float* msa  = (const float*)d_in[11];
  const float* w0   = (const float*)d_in[12];
  const float* s0   = (const float*)d_in[13];
  const float* b0   = (const float*)d_in[14];
  const float* w1   = (const float*)d_in[15];
  const float* s1   = (const float*)d_in[16];
  const float* b1   = (const float*)d_in[17];
  const float* w2   = (const float*)d_in[18];
  const float* s2   = (const float*)d_in[19];
  const float* b2   = (const float*)d_in[20];
  const float* c1w  = (const float*)d_in[21];
  const float* c1b  = (const float*)d_in[22];
  const float* bn1s = (const float*)d_in[23];
  const float* bn1b = (const float*)d_in[24];
  const float* c2w  = (const float*)d_in[25];
  const float* c2b  = (const float*)d_in[26];
  const float* bn2s = (const float*)d_in[27];
  const float* bn2b = (const float*)d_in[28];
  const float* c3w  = (const float*)d_in[29];
  const float* c3b  = (const float*)d_in[30];
  float* out = (float*)d_out;
  float* wsf = (float*)d_ws;

  if (ws_size >= WS_NEED_BYTES) {
    hipLaunchKernelGGL((prep_kernel<true>), dim3(16 + 1024 + 450 + 192 + 4096), dim3(256), 0, stream,
                       vote_xyz, vote_feat, w0, w1, w2, c1w, c2w, c3w,
                       pz, cz, pxy, cxy, pl, cl, az, axy, wsf, out);
    hipLaunchKernelGGL((proposal_kernel<true>), dim3(BB * NPROPN), dim3(64), 0, stream,
                       vote_xyz, vote_feat, wsf, msa,
                       s0, b0, s1, b1, s2, b2,
                       c1b, bn1s, bn1b, c2b, bn2s, bn2b, c3b, out);
  } else {
    hipLaunchKernelGGL((prep_kernel<false>), dim3(16 + 450 + 192 + 4096), dim3(256), 0, stream,
                       vote_xyz, vote_feat, w0, w1, w2, c1w, c2w, c3w,
                       pz, cz, pxy, cxy, pl, cl, az, axy, wsf, out);
    hipLaunchKernelGGL((proposal_kernel<false>), dim3(BB * NPROPN), dim3(64), 0, stream,
                       vote_xyz, vote_feat, wsf, msa,
                       s0, b0, s1, b1, s2, b2,
                       c1b, bn1s, bn1b, c2b, bn2s, bn2b, c3b, out);
  }
}

// Round 13
// 326.340 us; speedup vs baseline: 1.2176x; 1.2176x over previous
//
#include <hip/hip_runtime.h>

#define BB 16
#define KK 2048
#define NPROPN 256
#define NS 16
#define CSEED 256
#define CMLP 128
#define CIN 259
#define OUTCH 119
#define KZZ 1024

// output offsets in floats (concatenated tuple order)
#define O0  0UL
#define O1  8192UL
#define O2  20480UL
#define O3  69632UL
#define O4  118784UL
#define O5  192512UL
#define O6  413696UL
#define O7  487424UL
#define O8  585728UL
#define O9  4780032UL
#define O10 4829184UL
#define O11 4902912UL

// ws layout (floats)
#define WS_NEWXYZ 0
#define WS_W0T 12288
#define WS_W1T 45440
#define WS_W2T 61824
#define WS_C1T 78208
#define WS_C2T 94592
#define WS_C3T 110976
#define WS_FEATT 131072UL
#define WS_NEED_BYTES ((size_t)(WS_FEATT + (size_t)BB * KK * CSEED) * 4)

#define XROWS 131
#define XSTR (XROWS * 16)  // 2096 floats per wave buffer

// DPP argmax-reduce step on packed key (hi=dist bits (>=0), lo=~idx) — R5-proven
#define RSTEP(CTRL)                                                                          \
  {                                                                                          \
    unsigned shi = (unsigned)__builtin_amdgcn_update_dpp((int)hi, (int)hi, (CTRL), 0xF, 0xF, false); \
    unsigned slo = (unsigned)__builtin_amdgcn_update_dpp((int)lo, (int)lo, (CTRL), 0xF, 0xF, false); \
    bool gt = (shi > hi) || ((shi == hi) && (slo > lo));                                     \
    hi = gt ? shi : hi;                                                                      \
    lo = gt ? slo : lo;                                                                      \
  }

__device__ __forceinline__ void fma4(float4& a, float s, const float4& w) {
  a.x = fmaf(s, w.x, a.x); a.y = fmaf(s, w.y, a.y);
  a.z = fmaf(s, w.z, a.z); a.w = fmaf(s, w.w, a.w);
}
__device__ __forceinline__ float fget(const float4& v, int r) {
  return r == 0 ? v.x : (r == 1 ? v.y : (r == 2 ? v.z : v.w));
}
// swizzled LDS addr: element (row, s4) at row*16 + ((s4 ^ (row>>2)&3)<<2)
__device__ __forceinline__ int xadr(int row, int s4) {
  return row * 16 + (((s4) ^ ((row >> 2) & 3)) << 2);
}

template<bool TR>
__global__ __launch_bounds__(256) void prep_kernel(
    const float* __restrict__ xyz, const float* __restrict__ vote_feat,
    const float* __restrict__ w0, const float* __restrict__ w1, const float* __restrict__ w2,
    const float* __restrict__ c1w, const float* __restrict__ c2w, const float* __restrict__ c3w,
    const float* __restrict__ pz, const float* __restrict__ cz,
    const float* __restrict__ pxy, const float* __restrict__ cxy,
    const float* __restrict__ pl, const float* __restrict__ cl,
    const float* __restrict__ az, const float* __restrict__ axy,
    float* __restrict__ wsf, float* __restrict__ out) {
  constexpr int FPS_END = 16;
  constexpr int FEATT_END = FPS_END + (TR ? 1024 : 0);
  constexpr int TRW_END = FEATT_END + 450;
  constexpr int SURF_END = TRW_END + 192;

  const int bid = blockIdx.x;
  const int t = threadIdx.x;
  __shared__ float smem[8448];  // FPS: sxyz 6144 + nxb 768 ; transpose: [32][260] tile
  __shared__ float wvv[2][4];
  __shared__ int wii[2][4];

  if (bid < FPS_END) {
    // ---- FPS (R5-exact): 4 waves, 1 barrier/iter, new_xyz buffered in LDS ----
    const int b = bid;
    const float* p = xyz + (size_t)b * KK * 3;
    float* sxyz = smem;
    float* nxb = smem + 6144;
    const int lane = t & 63, w = t >> 6;
    float pxr[8], pyr[8], pzr[8], dd[8];
#pragma unroll
    for (int j = 0; j < 8; ++j) {
      int i = j * 256 + t;
      float x = p[i * 3 + 0], y = p[i * 3 + 1], z = p[i * 3 + 2];
      pxr[j] = x; pyr[j] = y; pzr[j] = z; dd[j] = 1e10f;
      sxyz[i * 3 + 0] = x; sxyz[i * 3 + 1] = y; sxyz[i * 3 + 2] = z;
    }
    __syncthreads();
    int cur = 0;
    for (int it = 0; it < NPROPN; ++it) {
      const int pb = it & 1;
      float cx = sxyz[cur * 3 + 0];
      float cy = sxyz[cur * 3 + 1];
      float cz2 = sxyz[cur * 3 + 2];
      if (t == 0) { nxb[it * 3 + 0] = cx; nxb[it * 3 + 1] = cy; nxb[it * 3 + 2] = cz2; }
      float best = -1.0f;
      int bidx = 0;
#pragma unroll
      for (int j = 0; j < 8; ++j) {
        float dx = __fsub_rn(pxr[j], cx);
        float dy = __fsub_rn(pyr[j], cy);
        float dz = __fsub_rn(pzr[j], cz2);
        float d = __fadd_rn(__fadd_rn(__fmul_rn(dx, dx), __fmul_rn(dy, dy)), __fmul_rn(dz, dz));
        float nd = fminf(dd[j], d);
        dd[j] = nd;
        if (nd > best) { best = nd; bidx = j * 256 + t; }  // strict >: first-index per lane
      }
      unsigned hi = __float_as_uint(best);
      unsigned lo = ~(unsigned)bidx;  // max(~idx) == min(idx) on dist ties
      RSTEP(0x111) RSTEP(0x112) RSTEP(0x114) RSTEP(0x118)  // row_shr 1,2,4,8
      RSTEP(0x142) RSTEP(0x143)                            // row_bcast15, row_bcast31
      if (lane == 63) { wvv[pb][w] = __uint_as_float(hi); wii[pb][w] = (int)lo; }
      __syncthreads();
      unsigned vh = __float_as_uint(wvv[pb][0]);
      unsigned vl = (unsigned)wii[pb][0];
#pragma unroll
      for (int q2 = 1; q2 < 4; ++q2) {
        unsigned ah = __float_as_uint(wvv[pb][q2]);
        unsigned al = (unsigned)wii[pb][q2];
        bool gt = (ah > vh) || ((ah == vh) && (al > vl));
        vh = gt ? ah : vh; vl = gt ? al : vl;
      }
      cur = (int)~vl;  // uniform across block
    }
    __syncthreads();
    float* nxw = wsf + WS_NEWXYZ + (size_t)b * NPROPN * 3;
    for (int i = t; i < NPROPN * 3; i += 256) nxw[i] = nxb[i];
    return;
  }

  if (TR && bid < FEATT_END) {
    // ---- vote_features transpose: [C][K] -> featT[b][k][C] ----
    int q = bid - FPS_END;
    int b = q >> 6, ck = q & 63;
    int k0 = ck << 5;
    float* tile = smem;  // [32][260]
    const float* src = vote_feat + ((size_t)b * CSEED + t) * KK + k0;
    float4 v[8];
#pragma unroll
    for (int j = 0; j < 8; ++j) v[j] = *(const float4*)(src + j * 4);
#pragma unroll
    for (int j = 0; j < 8; ++j) {
      tile[(j * 4 + 0) * 260 + t] = v[j].x;
      tile[(j * 4 + 1) * 260 + t] = v[j].y;
      tile[(j * 4 + 2) * 260 + t] = v[j].z;
      tile[(j * 4 + 3) * 260 + t] = v[j].w;
    }
    __syncthreads();
    float* dst = wsf + WS_FEATT + ((size_t)b * KK + k0) * CSEED;
    const int kk = t >> 3, cbase = (t & 7) << 2;
#pragma unroll
    for (int j = 0; j < 8; ++j) {
      int c = cbase + (j << 5);
      float4 u = make_float4(tile[kk * 260 + c], tile[kk * 260 + c + 1],
                             tile[kk * 260 + c + 2], tile[kk * 260 + c + 3]);
      *(float4*)(dst + (size_t)kk * CSEED + c) = u;
    }
    return;
  }

  if (bid < TRW_END) {
    // ---- weight transpose into ws ----
    int row = (bid - FEATT_END) * 2 + (t >> 7);
    int o = t & 127;
    if (row < 899) {
      float v; float* dst;
      if (row < 259)      { dst = wsf + WS_W0T + (size_t)row * 128; v = w0[(size_t)o * CIN + row]; }
      else if (row < 387) { int k = row - 259; dst = wsf + WS_W1T + (size_t)k * 128; v = w1[(size_t)o * 128 + k]; }
      else if (row < 515) { int k = row - 387; dst = wsf + WS_W2T + (size_t)k * 128; v = w2[(size_t)o * 128 + k]; }
      else if (row < 643) { int k = row - 515; dst = wsf + WS_C1T + (size_t)k * 128; v = c1w[(size_t)o * 128 + k]; }
      else if (row < 771) { int k = row - 643; dst = wsf + WS_C2T + (size_t)k * 128; v = c2w[(size_t)o * 128 + k]; }
      else                { int k = row - 771; dst = wsf + WS_C3T + (size_t)k * 128; v = (o < OUTCH) ? c3w[(size_t)o * 128 + k] : 0.f; }
      dst[o] = v;
    }
    return;
  }

  if (bid < SURF_END) {
    // ---- surface center selection ----
    int i = (bid - TRW_END) * 256 + t;
    int src = i / (BB * KZZ);
    int rem = i % (BB * KZZ);
    int b = rem / KZZ, k = rem % KZZ;
    const float* ps = (src == 0) ? pz : ((src == 1) ? pxy : pl);
    const float* pc = (src == 0) ? cz : ((src == 1) ? cxy : cl);
    float x0 = ps[((size_t)b * 2 + 0) * KZZ + k];
    float x1 = ps[((size_t)b * 2 + 1) * KZZ + k];
    float add = (x1 <= x0) ? 10.0f : 0.0f;
    size_t dst;
    if (src == 0)      dst = O7 + ((size_t)b * 2048 + k) * 3;
    else if (src == 1) dst = O7 + ((size_t)b * 2048 + 1024 + k) * 3;
    else               dst = O9 + ((size_t)b * KZZ + k) * 3;
    const float* c3 = pc + ((size_t)b * KZZ + k) * 3;
    out[dst + 0] = c3[0] + add;
    out[dst + 1] = c3[1] + add;
    out[dst + 2] = c3[2] + add;
    return;
  }

  {
    // ---- aggregated feature concat copy ----
    int i = (bid - SURF_END) * 256 + t;
    int q = i & 511;
    int bc = i >> 9;
    int half = q >> 8, k4 = q & 255;
    const float4* src = (const float4*)((half == 0) ? az : axy);
    float4 v = src[(size_t)bc * 256 + k4];
    float4* dst = (float4*)(out + O8);
    dst[(size_t)bc * 512 + q] = v;
  }
}

// ---- SLOW path (exact R8/R11 code): 16 samples, per-sh 8 samples x 4 cols ----
__device__ __forceinline__ void mlp_accum(const float* __restrict__ WT, int og, int sh,
                                          const float* __restrict__ xb, int K, float4* acc) {
  const float4* wp = (const float4*)WT + og;
  const int s4a = sh * 2, s4b = sh * 2 + 1;
#pragma unroll 4
  for (int k = 0; k < K; ++k) {
    float4 xa = *(const float4*)(xb + xadr(k, s4a));
    float4 xq = *(const float4*)(xb + xadr(k, s4b));
    float4 wv = wp[(size_t)k * 32];
    fma4(acc[0], xa.x, wv); fma4(acc[1], xa.y, wv);
    fma4(acc[2], xa.z, wv); fma4(acc[3], xa.w, wv);
    fma4(acc[4], xq.x, wv); fma4(acc[5], xq.y, wv);
    fma4(acc[6], xq.z, wv); fma4(acc[7], xq.w, wv);
  }
}

// ---- FAST path (total<=8): samples 0..7 only; sh halves split even/odd k. ----
// Per k-pair: 2 broadcast ds_read_b128 + 1KB contiguous W + 32 FMA (half the work).
__device__ __forceinline__ void mlp_accum_pair(const float* __restrict__ WT, int og, int sh,
                                               const float* __restrict__ xb, int K, float4* acc) {
  const float4* wp = (const float4*)WT + og;
#pragma unroll 4
  for (int k2 = 0; k2 < K; k2 += 2) {
    int myk = k2 + sh;
    int mk = myk < K ? myk : (K - 1);  // clamp keeps loads in-bounds (odd K tail)
    float4 xa = *(const float4*)(xb + xadr(mk, 0));
    float4 xq = *(const float4*)(xb + xadr(mk, 1));
    float4 wv = wp[(size_t)mk * 32];
    if (myk < K) {
      fma4(acc[0], xa.x, wv); fma4(acc[1], xa.y, wv);
      fma4(acc[2], xa.z, wv); fma4(acc[3], xa.w, wv);
      fma4(acc[4], xq.x, wv); fma4(acc[5], xq.y, wv);
      fma4(acc[6], xq.z, wv); fma4(acc[7], xq.w, wv);
    }
  }
}

__device__ __forceinline__ void pair_combine(float4* acc) {
#pragma unroll
  for (int i = 0; i < 8; ++i) {
    acc[i].x += __shfl_xor(acc[i].x, 32);
    acc[i].y += __shfl_xor(acc[i].y, 32);
    acc[i].z += __shfl_xor(acc[i].z, 32);
    acc[i].w += __shfl_xor(acc[i].w, 32);
  }
}

__device__ __forceinline__ void mlp_storeh(const float* __restrict__ scv, const float* __restrict__ bbv,
                                           int og, int sh, float* __restrict__ xb,
                                           const float4* __restrict__ acc) {
  float4 s4v = *(const float4*)(scv + (og << 2));
  float4 b4v = *(const float4*)(bbv + (og << 2));
#pragma unroll
  for (int r = 0; r < 4; ++r) {
    float ss = fget(s4v, r), bv = fget(b4v, r);
    float4 lo, hi;
    lo.x = fmaf(fget(acc[0], r), ss, bv); lo.x = lo.x > 0.f ? lo.x : 0.f;
    lo.y = fmaf(fget(acc[1], r), ss, bv); lo.y = lo.y > 0.f ? lo.y : 0.f;
    lo.z = fmaf(fget(acc[2], r), ss, bv); lo.z = lo.z > 0.f ? lo.z : 0.f;
    lo.w = fmaf(fget(acc[3], r), ss, bv); lo.w = lo.w > 0.f ? lo.w : 0.f;
    hi.x = fmaf(fget(acc[4], r), ss, bv); hi.x = hi.x > 0.f ? hi.x : 0.f;
    hi.y = fmaf(fget(acc[5], r), ss, bv); hi.y = hi.y > 0.f ? hi.y : 0.f;
    hi.z = fmaf(fget(acc[6], r), ss, bv); hi.z = hi.z > 0.f ? hi.z : 0.f;
    hi.w = fmaf(fget(acc[7], r), ss, bv); hi.w = hi.w > 0.f ? hi.w : 0.f;
    int row = (og << 2) + r;
    *(float4*)(xb + xadr(row, sh * 2)) = lo;
    *(float4*)(xb + xadr(row, sh * 2 + 1)) = hi;
  }
}

template<bool TR>
__global__ __launch_bounds__(256, 4) void proposal_kernel(
    const float* __restrict__ vote_xyz, const float* __restrict__ vote_feat,
    const float* __restrict__ wsf, const float* __restrict__ msa,
    const float* __restrict__ s0, const float* __restrict__ b0,
    const float* __restrict__ s1, const float* __restrict__ b1,
    const float* __restrict__ s2, const float* __restrict__ b2,
    const float* __restrict__ c1b, const float* __restrict__ bn1s, const float* __restrict__ bn1b,
    const float* __restrict__ c2b, const float* __restrict__ bn2s, const float* __restrict__ bn2b,
    const float* __restrict__ c3b,
    float* __restrict__ out) {
  __shared__ __align__(16) float Xbuf[4 * XSTR];  // per-wave 131-row chunk / H buffer / epilogue scratch
  __shared__ int sel_s[4][NS];
  __shared__ float sc_s[4][3], sh_s[4][3];
  __shared__ int scls_s[4];

  const int t = threadIdx.x;
  const int w = t >> 6, l = t & 63;
  const int b = blockIdx.x >> 6;
  const int pp = ((blockIdx.x & 63) << 2) + w;
  const int sh = l >> 5, og = l & 31;
  float* Xw = Xbuf + w * XSTR;
  // epilogue overlays into Xw (dead after MLP; wave-private in-order DS)
  float* feat_p = Xw;          // 128
  float* n1_p   = Xw + 128;    // 128
  float* n2_p   = Xw + 256;    // 128
  float* ntv_p  = Xw + 384;    // 119 (pad to 120)

  const float* nx = wsf + WS_NEWXYZ + ((size_t)b * NPROPN + pp) * 3;
  const float cx = nx[0], cy = nx[1], cz = nx[2];
  const float* px = vote_xyz + (size_t)b * KK * 3;
  const float RR = 0.09000000357627869f;  // f32(0.3f*0.3f)

  // ---- ball query: first <=16 in-radius indices, ascending; batched loads ----
  int total = 0;
  {
    for (int j0 = 0; j0 < 32 && total < NS; j0 += 8) {
      float dq[8];
#pragma unroll
      for (int jj = 0; jj < 8; ++jj) {
        int i = ((j0 + jj) << 6) + l;
        float dx = __fsub_rn(px[i * 3 + 0], cx);
        float dy = __fsub_rn(px[i * 3 + 1], cy);
        float dz = __fsub_rn(px[i * 3 + 2], cz);
        dq[jj] = __fadd_rn(__fadd_rn(__fmul_rn(dx, dx), __fmul_rn(dy, dy)), __fmul_rn(dz, dz));
      }
#pragma unroll
      for (int jj = 0; jj < 8; ++jj) {
        bool in = (dq[jj] <= RR);
        unsigned long long bal = __ballot(in);
        if (in) {
          int pos = total + __popcll(bal & ((1ull << l) - 1ull));
          if (pos < NS) sel_s[w][pos] = ((j0 + jj) << 6) + l;
        }
        total += __popcll(bal);
      }
    }
    if (l == 0 && total < NS) {
      int first = (total > 0) ? sel_s[w][0] : 0;
      for (int i = total; i < NS; ++i) sel_s[w][i] = first;
    }
    __builtin_amdgcn_wave_barrier();
  }

  // ---- gather chunk0 (global rows 0..130) + prefetch chunk1 into regs ----
  float4 pf[8];
  {
    const int s = l >> 2, q = l & 3;
    const int idx = sel_s[w][s];
    const int s4 = s >> 2, se = s & 3;
    if (q < 3) {
      float pv = px[idx * 3 + q];
      float cv = (q == 0) ? cx : ((q == 1) ? cy : cz);
      Xw[xadr(q, s4) + se] = __fdiv_rn(__fsub_rn(pv, cv), 0.3f);
    }
    if constexpr (TR) {
      const float* fr = wsf + WS_FEATT + ((size_t)b * KK + idx) * CSEED;
#pragma unroll
      for (int m = 0; m < 8; ++m) {
        int c = (m << 4) + (q << 2);
        float4 v = *(const float4*)(fr + c);
        Xw[xadr(3 + c + 0, s4) + se] = v.x;
        Xw[xadr(3 + c + 1, s4) + se] = v.y;
        Xw[xadr(3 + c + 2, s4) + se] = v.z;
        Xw[xadr(3 + c + 3, s4) + se] = v.w;
      }
#pragma unroll
      for (int m = 0; m < 8; ++m) pf[m] = *(const float4*)(fr + 128 + (m << 4) + (q << 2));
    } else {
      const float* fb = vote_feat + (size_t)b * CSEED * KK + idx;
#pragma unroll
      for (int m = 0; m < 8; ++m) {
        int c = (m << 4) + (q << 2);
        Xw[xadr(3 + c + 0, s4) + se] = fb[(size_t)(c + 0) * KK];
        Xw[xadr(3 + c + 1, s4) + se] = fb[(size_t)(c + 1) * KK];
        Xw[xadr(3 + c + 2, s4) + se] = fb[(size_t)(c + 2) * KK];
        Xw[xadr(3 + c + 3, s4) + se] = fb[(size_t)(c + 3) * KK];
      }
#pragma unroll
      for (int m = 0; m < 8; ++m) {
        int c = 128 + (m << 4) + (q << 2);
        pf[m].x = fb[(size_t)(c + 0) * KK];
        pf[m].y = fb[(size_t)(c + 1) * KK];
        pf[m].z = fb[(size_t)(c + 2) * KK];
        pf[m].w = fb[(size_t)(c + 3) * KK];
      }
    }
    __builtin_amdgcn_wave_barrier();
  }

  auto write_chunk1 = [&]() {
    const int s = l >> 2, q = l & 3;
    const int s4 = s >> 2, se = s & 3;
#pragma unroll
    for (int m = 0; m < 8; ++m) {
      int c = (m << 4) + (q << 2);
      Xw[xadr(c + 0, s4) + se] = pf[m].x;
      Xw[xadr(c + 1, s4) + se] = pf[m].y;
      Xw[xadr(c + 2, s4) + se] = pf[m].z;
      Xw[xadr(c + 3, s4) + se] = pf[m].w;
    }
  };

  float4 acc[8];
#pragma unroll
  for (int i = 0; i < 8; ++i) acc[i] = make_float4(0.f, 0.f, 0.f, 0.f);

  if (total <= 8) {
    // ======== FAST path: only samples 0..7 matter (pads duplicate sel[0]) ========
    mlp_accum_pair(wsf + WS_W0T, og, sh, Xw, 131, acc);
    __builtin_amdgcn_wave_barrier();
    write_chunk1();
    __builtin_amdgcn_wave_barrier();
    mlp_accum_pair(wsf + WS_W0T + 131 * 128, og, sh, Xw, 128, acc);
    pair_combine(acc);
    mlp_storeh(s0, b0, og, sh, Xw, acc);
    __builtin_amdgcn_wave_barrier();
#pragma unroll
    for (int i = 0; i < 8; ++i) acc[i] = make_float4(0.f, 0.f, 0.f, 0.f);
    mlp_accum_pair(wsf + WS_W1T, og, sh, Xw, 128, acc);
    pair_combine(acc);
    mlp_storeh(s1, b1, og, sh, Xw, acc);
    __builtin_amdgcn_wave_barrier();
#pragma unroll
    for (int i = 0; i < 8; ++i) acc[i] = make_float4(0.f, 0.f, 0.f, 0.f);
    mlp_accum_pair(wsf + WS_W2T, og, sh, Xw, 128, acc);
    pair_combine(acc);
  } else {
    // ======== SLOW path: exact R11 code ========
    mlp_accum(wsf + WS_W0T, og, sh, Xw, 131, acc);
    __builtin_amdgcn_wave_barrier();
    write_chunk1();
    __builtin_amdgcn_wave_barrier();
    mlp_accum(wsf + WS_W0T + 131 * 128, og, sh, Xw, 128, acc);
    mlp_storeh(s0, b0, og, sh, Xw, acc);
    __builtin_amdgcn_wave_barrier();
#pragma unroll
    for (int i = 0; i < 8; ++i) acc[i] = make_float4(0.f, 0.f, 0.f, 0.f);
    mlp_accum(wsf + WS_W1T, og, sh, Xw, 128, acc);
    mlp_storeh(s1, b1, og, sh, Xw, acc);
    __builtin_amdgcn_wave_barrier();
#pragma unroll
    for (int i = 0; i < 8; ++i) acc[i] = make_float4(0.f, 0.f, 0.f, 0.f);
    mlp_accum(wsf + WS_W2T, og, sh, Xw, 128, acc);
  }

  // ---- epilogue: scale/bias/relu + maxpool (shared; fast path acc is combined) ----
  float mr[4];
  {
    float4 s4v = *(const float4*)(s2 + (og << 2));
    float4 b4v = *(const float4*)(b2 + (og << 2));
#pragma unroll
    for (int r = 0; r < 4; ++r) {
      float ss = fget(s4v, r), bv = fget(b4v, r);
      float m = 0.f;  // relu floor
#pragma unroll
      for (int i = 0; i < 8; ++i) m = fmaxf(m, fmaf(fget(acc[i], r), ss, bv));
      mr[r] = fmaxf(m, __shfl_xor(m, 32));
    }
  }
  __builtin_amdgcn_wave_barrier();  // all Xw reads (L2) done before overlay writes
  if (sh == 0) *(float4*)(feat_p + (og << 2)) = make_float4(mr[0], mr[1], mr[2], mr[3]);
  __builtin_amdgcn_wave_barrier();

  // ---- obj_surface_feature tile x6 ----
  {
    float* o11 = out + O11 + (size_t)b * CMLP * 1536;
#pragma unroll
    for (int r = 0; r < 4; ++r) {
      size_t rowb = (size_t)((og << 2) + r) * 1536 + pp;
#pragma unroll
      for (int rr2 = 0; rr2 < 3; ++rr2) {
        int rr = sh * 3 + rr2;
        o11[rowb + rr * 256] = mr[r];
      }
    }
  }

  // ---- conv chain (per-wave; weights from global ws, coalesced) ----
  {
    const float* C1T = wsf + WS_C1T;
    float a0 = 0.f, a1 = 0.f;
#pragma unroll 4
    for (int k = 0; k < CMLP; ++k) {
      float f = feat_p[k];
      float2 wv = *(const float2*)(C1T + (size_t)k * 128 + (l << 1));
      a0 = fmaf(f, wv.x, a0); a1 = fmaf(f, wv.y, a1);
    }
    int o0 = l << 1, o1 = o0 + 1;
    float v0 = fmaf(a0 + c1b[o0], bn1s[o0], bn1b[o0]); v0 = v0 > 0.f ? v0 : 0.f;
    float v1 = fmaf(a1 + c1b[o1], bn1s[o1], bn1b[o1]); v1 = v1 > 0.f ? v1 : 0.f;
    *(float2*)(n1_p + o0) = make_float2(v0, v1);
    __builtin_amdgcn_wave_barrier();
  }
  {
    const float* C2T = wsf + WS_C2T;
    float a0 = 0.f, a1 = 0.f;
#pragma unroll 4
    for (int k = 0; k < CMLP; ++k) {
      float f = n1_p[k];
      float2 wv = *(const float2*)(C2T + (size_t)k * 128 + (l << 1));
      a0 = fmaf(f, wv.x, a0); a1 = fmaf(f, wv.y, a1);
    }
    int o0 = l << 1, o1 = o0 + 1;
    float v0 = fmaf(a0 + c2b[o0], bn2s[o0], bn2b[o0]); v0 = v0 > 0.f ? v0 : 0.f;
    float v1 = fmaf(a1 + c2b[o1], bn2s[o1], bn2b[o1]); v1 = v1 > 0.f ? v1 : 0.f;
    *(float2*)(n2_p + o0) = make_float2(v0, v1);
    __builtin_amdgcn_wave_barrier();
  }
  {
    const float* C3T = wsf + WS_C3T;
    float a0 = 0.f, a1 = 0.f;
#pragma unroll 4
    for (int k = 0; k < CMLP; ++k) {
      float f = n2_p[k];
      float2 wv = *(const float2*)(C3T + (size_t)k * 128 + (l << 1));
      a0 = fmaf(f, wv.x, a0); a1 = fmaf(f, wv.y, a1);
    }
    int o0 = l << 1, o1 = o0 + 1;
    float bb0 = (o0 < OUTCH) ? c3b[o0] : 0.f;
    float bb1 = (o1 < OUTCH) ? c3b[o1] : 0.f;
    *(float2*)(ntv_p + o0) = make_float2(a0 + bb0, a1 + bb1);
    __builtin_amdgcn_wave_barrier();
  }

  // ---- heads (wave-private) ----
  {
    const size_t bp = (size_t)b * NPROPN + pp;
    if (l < 2) out[O0 + bp * 2 + l] = ntv_p[l];
    if (l < 3) {
      float cv = ((l == 0) ? cx : ((l == 1) ? cy : cz)) + ntv_p[2 + l];
      sc_s[w][l] = cv;
      out[O1 + bp * 3 + l] = cv;
    }
    if (l < 12) {
      out[O2 + bp * 12 + l] = ntv_p[5 + l];
      out[O3 + bp * 12 + l] = ntv_p[17 + l] * 0.2617993877991494f;
    }
    if (l < 18) {
      out[O4 + bp * 18 + l] = ntv_p[29 + l];
      out[O6 + bp * 18 + l] = ntv_p[101 + l];
    }
    if (l < 54) out[O5 + bp * 54 + l] = ntv_p[47 + l] * msa[l];
    if (l == 0) {
      float bvv = ntv_p[29]; int bii = 0;
      for (int i2 = 1; i2 < 18; ++i2)
        if (ntv_p[29 + i2] > bvv) { bvv = ntv_p[29 + i2]; bii = i2; }
      scls_s[w] = bii;
    }
    __builtin_amdgcn_wave_barrier();
    if (l < 3) {
      int cls = scls_s[w];
      float m = msa[cls * 3 + l];
      sh_s[w][l] = fmaf(ntv_p[47 + cls * 3 + l], m, m) * 0.5f;
    }
    __builtin_amdgcn_wave_barrier();
    if (l < 18) {
      const int r = l / 3, j2 = l % 3;
      const int axis[6] = {2, 2, 1, 1, 0, 0};
      float v = sc_s[w][j2];
      if (j2 == axis[r]) v = (r & 1) ? (v - sh_s[w][j2]) : (v + sh_s[w][j2]);
      out[O10 + (size_t)b * 4608 + (size_t)(r * 256 + pp) * 3 + j2] = v;
    }
  }
}

extern "C" void kernel_launch(void* const* d_in, const int* in_sizes, int n_in,
                              void* d_out, int out_size, void* d_ws, size_t ws_size,
                              hipStream_t stream) {
  (void)in_sizes; (void)n_in; (void)out_size;
  const float* vote_xyz = (const float*)d_in[0];
  const float* vote_feat = (const float*)d_in[1];
  const float* pz   = (const float*)d_in[2];
  const float* cz   = (const float*)d_in[3];
  const float* az   = (const float*)d_in[4];
  const float* pxy  = (const float*)d_in[5];
  const float* cxy  = (const float*)d_in[6];
  const float* axy  = (const float*)d_in[7];
  const float* pl   = (const float*)d_in[8];
  const float* cl   = (const float*)d_in[9];
  const float* msa  = (const float*)d_in[11];
  const float* w0   = (const float*)d_in[12];
  const float* s0   = (const float*)d_in[13];
  const float* b0   = (const float*)d_in[14];
  const float* w1   = (const float*)d_in[15];
  const float* s1   = (const float*)d_in[16];
  const float* b1   = (const float*)d_in[17];
  const float* w2   = (const float*)d_in[18];
  const float* s2   = (const float*)d_in[19];
  const float* b2   = (const float*)d_in[20];
  const float* c1w  = (const float*)d_in[21];
  const float* c1b  = (const float*)d_in[22];
  const float* bn1s = (const float*)d_in[23];
  const float* bn1b = (const float*)d_in[24];
  const float* c2w  = (const float*)d_in[25];
  const float* c2b  = (const float*)d_in[26];
  const float* bn2s = (const float*)d_in[27];
  const float* bn2b = (const float*)d_in[28];
  const float* c3w  = (const float*)d_in[29];
  const float* c3b  = (const float*)d_in[30];
  float* out = (float*)d_out;
  float* wsf = (float*)d_ws;

  if (ws_size >= WS_NEED_BYTES) {
    hipLaunchKernelGGL((prep_kernel<true>), dim3(16 + 1024 + 450 + 192 + 4096), dim3(256), 0, stream,
                       vote_xyz, vote_feat, w0, w1, w2, c1w, c2w, c3w,
                       pz, cz, pxy, cxy, pl, cl, az, axy, wsf, out);
    hipLaunchKernelGGL((proposal_kernel<true>), dim3(BB * NPROPN / 4), dim3(256), 0, stream,
                       vote_xyz, vote_feat, wsf, msa,
                       s0, b0, s1, b1, s2, b2,
                       c1b, bn1s, bn1b, c2b, bn2s, bn2b, c3b, out);
  } else {
    hipLaunchKernelGGL((prep_kernel<false>), dim3(16 + 450 + 192 + 4096), dim3(256), 0, stream,
                       vote_xyz, vote_feat, w0, w1, w2, c1w, c2w, c3w,
                       pz, cz, pxy, cxy, pl, cl, az, axy, wsf, out);
    hipLaunchKernelGGL((proposal_kernel<false>), dim3(BB * NPROPN / 4), dim3(256), 0, stream,
                       vote_xyz, vote_feat, wsf, msa,
                       s0, b0, s1, b1, s2, b2,
                       c1b, bn1s, bn1b, c2b, bn2s, bn2b, c3b, out);
  }
}

// Round 14
// 310.295 us; speedup vs baseline: 1.2806x; 1.0517x over previous
//
#include <hip/hip_runtime.h>

#define BB 16
#define KK 2048
#define NPROPN 256
#define NS 16
#define CSEED 256
#define CMLP 128
#define CIN 259
#define OUTCH 119
#define KZZ 1024

// output offsets in floats (concatenated tuple order)
#define O0  0UL
#define O1  8192UL
#define O2  20480UL
#define O3  69632UL
#define O4  118784UL
#define O5  192512UL
#define O6  413696UL
#define O7  487424UL
#define O8  585728UL
#define O9  4780032UL
#define O10 4829184UL
#define O11 4902912UL

// ws layout (floats)
#define WS_NEWXYZ 0
#define WS_W0T 12288
#define WS_W1T 45440
#define WS_W2T 61824
#define WS_C1T 78208
#define WS_C2T 94592
#define WS_C3T 110976
#define WS_FEATT 131072UL
#define WS_NEED_BYTES ((size_t)(WS_FEATT + (size_t)BB * KK * CSEED) * 4)

#define XROWS 131
#define XSTR (XROWS * 16)  // 2096 floats per wave buffer

// DPP argmax-reduce step on packed key (hi=dist bits (>=0), lo=~idx) — R5-proven
#define RSTEP(CTRL)                                                                          \
  {                                                                                          \
    unsigned shi = (unsigned)__builtin_amdgcn_update_dpp((int)hi, (int)hi, (CTRL), 0xF, 0xF, false); \
    unsigned slo = (unsigned)__builtin_amdgcn_update_dpp((int)lo, (int)lo, (CTRL), 0xF, 0xF, false); \
    bool gt = (shi > hi) || ((shi == hi) && (slo > lo));                                     \
    hi = gt ? shi : hi;                                                                      \
    lo = gt ? slo : lo;                                                                      \
  }

__device__ __forceinline__ void fma4(float4& a, float s, const float4& w) {
  a.x = fmaf(s, w.x, a.x); a.y = fmaf(s, w.y, a.y);
  a.z = fmaf(s, w.z, a.z); a.w = fmaf(s, w.w, a.w);
}
__device__ __forceinline__ float fget(const float4& v, int r) {
  return r == 0 ? v.x : (r == 1 ? v.y : (r == 2 ? v.z : v.w));
}
// swizzled LDS addr: element (row, s4) at row*16 + ((s4 ^ (row>>2)&3)<<2)
__device__ __forceinline__ int xadr(int row, int s4) {
  return row * 16 + (((s4) ^ ((row >> 2) & 3)) << 2);
}

template<bool TR>
__global__ __launch_bounds__(256) void prep_kernel(
    const float* __restrict__ xyz, const float* __restrict__ vote_feat,
    const float* __restrict__ w0, const float* __restrict__ w1, const float* __restrict__ w2,
    const float* __restrict__ c1w, const float* __restrict__ c2w, const float* __restrict__ c3w,
    const float* __restrict__ pz, const float* __restrict__ cz,
    const float* __restrict__ pxy, const float* __restrict__ cxy,
    const float* __restrict__ pl, const float* __restrict__ cl,
    const float* __restrict__ az, const float* __restrict__ axy,
    float* __restrict__ wsf, float* __restrict__ out) {
  constexpr int FPS_END = 16;
  constexpr int FEATT_END = FPS_END + (TR ? 1024 : 0);
  constexpr int TRW_END = FEATT_END + 450;
  constexpr int SURF_END = TRW_END + 192;

  const int bid = blockIdx.x;
  const int t = threadIdx.x;
  __shared__ float smem[8448];  // FPS: sxyz 6144 + nxb 768 ; transpose: [32][260] tile
  __shared__ float wvv[2][4];
  __shared__ int wii[2][4];

  if (bid < FPS_END) {
    // ---- FPS (R5-exact): 4 waves, 1 barrier/iter, new_xyz buffered in LDS ----
    const int b = bid;
    const float* p = xyz + (size_t)b * KK * 3;
    float* sxyz = smem;
    float* nxb = smem + 6144;
    const int lane = t & 63, w = t >> 6;
    float pxr[8], pyr[8], pzr[8], dd[8];
#pragma unroll
    for (int j = 0; j < 8; ++j) {
      int i = j * 256 + t;
      float x = p[i * 3 + 0], y = p[i * 3 + 1], z = p[i * 3 + 2];
      pxr[j] = x; pyr[j] = y; pzr[j] = z; dd[j] = 1e10f;
      sxyz[i * 3 + 0] = x; sxyz[i * 3 + 1] = y; sxyz[i * 3 + 2] = z;
    }
    __syncthreads();
    int cur = 0;
    for (int it = 0; it < NPROPN; ++it) {
      const int pb = it & 1;
      float cx = sxyz[cur * 3 + 0];
      float cy = sxyz[cur * 3 + 1];
      float cz2 = sxyz[cur * 3 + 2];
      if (t == 0) { nxb[it * 3 + 0] = cx; nxb[it * 3 + 1] = cy; nxb[it * 3 + 2] = cz2; }
      float best = -1.0f;
      int bidx = 0;
#pragma unroll
      for (int j = 0; j < 8; ++j) {
        float dx = __fsub_rn(pxr[j], cx);
        float dy = __fsub_rn(pyr[j], cy);
        float dz = __fsub_rn(pzr[j], cz2);
        float d = __fadd_rn(__fadd_rn(__fmul_rn(dx, dx), __fmul_rn(dy, dy)), __fmul_rn(dz, dz));
        float nd = fminf(dd[j], d);
        dd[j] = nd;
        if (nd > best) { best = nd; bidx = j * 256 + t; }  // strict >: first-index per lane
      }
      unsigned hi = __float_as_uint(best);
      unsigned lo = ~(unsigned)bidx;  // max(~idx) == min(idx) on dist ties
      RSTEP(0x111) RSTEP(0x112) RSTEP(0x114) RSTEP(0x118)  // row_shr 1,2,4,8
      RSTEP(0x142) RSTEP(0x143)                            // row_bcast15, row_bcast31
      if (lane == 63) { wvv[pb][w] = __uint_as_float(hi); wii[pb][w] = (int)lo; }
      __syncthreads();
      unsigned vh = __float_as_uint(wvv[pb][0]);
      unsigned vl = (unsigned)wii[pb][0];
#pragma unroll
      for (int q2 = 1; q2 < 4; ++q2) {
        unsigned ah = __float_as_uint(wvv[pb][q2]);
        unsigned al = (unsigned)wii[pb][q2];
        bool gt = (ah > vh) || ((ah == vh) && (al > vl));
        vh = gt ? ah : vh; vl = gt ? al : vl;
      }
      cur = (int)~vl;  // uniform across block
    }
    __syncthreads();
    float* nxw = wsf + WS_NEWXYZ + (size_t)b * NPROPN * 3;
    for (int i = t; i < NPROPN * 3; i += 256) nxw[i] = nxb[i];
    return;
  }

  if (TR && bid < FEATT_END) {
    // ---- vote_features transpose: [C][K] -> featT[b][k][C] ----
    int q = bid - FPS_END;
    int b = q >> 6, ck = q & 63;
    int k0 = ck << 5;
    float* tile = smem;  // [32][260]
    const float* src = vote_feat + ((size_t)b * CSEED + t) * KK + k0;
    float4 v[8];
#pragma unroll
    for (int j = 0; j < 8; ++j) v[j] = *(const float4*)(src + j * 4);
#pragma unroll
    for (int j = 0; j < 8; ++j) {
      tile[(j * 4 + 0) * 260 + t] = v[j].x;
      tile[(j * 4 + 1) * 260 + t] = v[j].y;
      tile[(j * 4 + 2) * 260 + t] = v[j].z;
      tile[(j * 4 + 3) * 260 + t] = v[j].w;
    }
    __syncthreads();
    float* dst = wsf + WS_FEATT + ((size_t)b * KK + k0) * CSEED;
    const int kk = t >> 3, cbase = (t & 7) << 2;
#pragma unroll
    for (int j = 0; j < 8; ++j) {
      int c = cbase + (j << 5);
      float4 u = make_float4(tile[kk * 260 + c], tile[kk * 260 + c + 1],
                             tile[kk * 260 + c + 2], tile[kk * 260 + c + 3]);
      *(float4*)(dst + (size_t)kk * CSEED + c) = u;
    }
    return;
  }

  if (bid < TRW_END) {
    // ---- weight transpose into ws ----
    int row = (bid - FEATT_END) * 2 + (t >> 7);
    int o = t & 127;
    if (row < 899) {
      float v; float* dst;
      if (row < 259)      { dst = wsf + WS_W0T + (size_t)row * 128; v = w0[(size_t)o * CIN + row]; }
      else if (row < 387) { int k = row - 259; dst = wsf + WS_W1T + (size_t)k * 128; v = w1[(size_t)o * 128 + k]; }
      else if (row < 515) { int k = row - 387; dst = wsf + WS_W2T + (size_t)k * 128; v = w2[(size_t)o * 128 + k]; }
      else if (row < 643) { int k = row - 515; dst = wsf + WS_C1T + (size_t)k * 128; v = c1w[(size_t)o * 128 + k]; }
      else if (row < 771) { int k = row - 643; dst = wsf + WS_C2T + (size_t)k * 128; v = c2w[(size_t)o * 128 + k]; }
      else                { int k = row - 771; dst = wsf + WS_C3T + (size_t)k * 128; v = (o < OUTCH) ? c3w[(size_t)o * 128 + k] : 0.f; }
      dst[o] = v;
    }
    return;
  }

  if (bid < SURF_END) {
    // ---- surface center selection ----
    int i = (bid - TRW_END) * 256 + t;
    int src = i / (BB * KZZ);
    int rem = i % (BB * KZZ);
    int b = rem / KZZ, k = rem % KZZ;
    const float* ps = (src == 0) ? pz : ((src == 1) ? pxy : pl);
    const float* pc = (src == 0) ? cz : ((src == 1) ? cxy : cl);
    float x0 = ps[((size_t)b * 2 + 0) * KZZ + k];
    float x1 = ps[((size_t)b * 2 + 1) * KZZ + k];
    float add = (x1 <= x0) ? 10.0f : 0.0f;
    size_t dst;
    if (src == 0)      dst = O7 + ((size_t)b * 2048 + k) * 3;
    else if (src == 1) dst = O7 + ((size_t)b * 2048 + 1024 + k) * 3;
    else               dst = O9 + ((size_t)b * KZZ + k) * 3;
    const float* c3 = pc + ((size_t)b * KZZ + k) * 3;
    out[dst + 0] = c3[0] + add;
    out[dst + 1] = c3[1] + add;
    out[dst + 2] = c3[2] + add;
    return;
  }

  {
    // ---- aggregated feature concat copy ----
    int i = (bid - SURF_END) * 256 + t;
    int q = i & 511;
    int bc = i >> 9;
    int half = q >> 8, k4 = q & 255;
    const float4* src = (const float4*)((half == 0) ? az : axy);
    float4 v = src[(size_t)bc * 256 + k4];
    float4* dst = (float4*)(out + O8);
    dst[(size_t)bc * 512 + q] = v;
  }
}

// ---- SLOW path (exact R8/R11 code): 16 samples, per-sh 8 samples x 4 cols ----
__device__ __forceinline__ void mlp_accum(const float* __restrict__ WT, int og, int sh,
                                          const float* __restrict__ xb, int K, float4* acc) {
  const float4* wp = (const float4*)WT + og;
  const int s4a = sh * 2, s4b = sh * 2 + 1;
#pragma unroll 4
  for (int k = 0; k < K; ++k) {
    float4 xa = *(const float4*)(xb + xadr(k, s4a));
    float4 xq = *(const float4*)(xb + xadr(k, s4b));
    float4 wv = wp[(size_t)k * 32];
    fma4(acc[0], xa.x, wv); fma4(acc[1], xa.y, wv);
    fma4(acc[2], xa.z, wv); fma4(acc[3], xa.w, wv);
    fma4(acc[4], xq.x, wv); fma4(acc[5], xq.y, wv);
    fma4(acc[6], xq.z, wv); fma4(acc[7], xq.w, wv);
  }
}

// ---- FAST path (total<=8): samples 0..7 only; sh halves split even/odd k. ----
__device__ __forceinline__ void mlp_accum_pair(const float* __restrict__ WT, int og, int sh,
                                               const float* __restrict__ xb, int K, float4* acc) {
  const float4* wp = (const float4*)WT + og;
#pragma unroll 4
  for (int k2 = 0; k2 < K; k2 += 2) {
    int myk = k2 + sh;
    int mk = myk < K ? myk : (K - 1);  // clamp keeps loads in-bounds (odd K tail)
    float4 xa = *(const float4*)(xb + xadr(mk, 0));
    float4 xq = *(const float4*)(xb + xadr(mk, 1));
    float4 wv = wp[(size_t)mk * 32];
    if (myk < K) {
      fma4(acc[0], xa.x, wv); fma4(acc[1], xa.y, wv);
      fma4(acc[2], xa.z, wv); fma4(acc[3], xa.w, wv);
      fma4(acc[4], xq.x, wv); fma4(acc[5], xq.y, wv);
      fma4(acc[6], xq.z, wv); fma4(acc[7], xq.w, wv);
    }
  }
}

__device__ __forceinline__ void pair_combine(float4* acc) {
#pragma unroll
  for (int i = 0; i < 8; ++i) {
    acc[i].x += __shfl_xor(acc[i].x, 32);
    acc[i].y += __shfl_xor(acc[i].y, 32);
    acc[i].z += __shfl_xor(acc[i].z, 32);
    acc[i].w += __shfl_xor(acc[i].w, 32);
  }
}

__device__ __forceinline__ void mlp_storeh(const float* __restrict__ scv, const float* __restrict__ bbv,
                                           int og, int sh, float* __restrict__ xb,
                                           const float4* __restrict__ acc) {
  float4 s4v = *(const float4*)(scv + (og << 2));
  float4 b4v = *(const float4*)(bbv + (og << 2));
#pragma unroll
  for (int r = 0; r < 4; ++r) {
    float ss = fget(s4v, r), bv = fget(b4v, r);
    float4 lo, hi;
    lo.x = fmaf(fget(acc[0], r), ss, bv); lo.x = lo.x > 0.f ? lo.x : 0.f;
    lo.y = fmaf(fget(acc[1], r), ss, bv); lo.y = lo.y > 0.f ? lo.y : 0.f;
    lo.z = fmaf(fget(acc[2], r), ss, bv); lo.z = lo.z > 0.f ? lo.z : 0.f;
    lo.w = fmaf(fget(acc[3], r), ss, bv); lo.w = lo.w > 0.f ? lo.w : 0.f;
    hi.x = fmaf(fget(acc[4], r), ss, bv); hi.x = hi.x > 0.f ? hi.x : 0.f;
    hi.y = fmaf(fget(acc[5], r), ss, bv); hi.y = hi.y > 0.f ? hi.y : 0.f;
    hi.z = fmaf(fget(acc[6], r), ss, bv); hi.z = hi.z > 0.f ? hi.z : 0.f;
    hi.w = fmaf(fget(acc[7], r), ss, bv); hi.w = hi.w > 0.f ? hi.w : 0.f;
    int row = (og << 2) + r;
    *(float4*)(xb + xadr(row, sh * 2)) = lo;
    *(float4*)(xb + xadr(row, sh * 2 + 1)) = hi;
  }
}

// Conv 128->128: split-k across half-waves, float4 W loads, unroll 8 (8 loads/wait).
// Lane (og, sh) computes outputs og*4..+3 over k = 2j+sh; combine via shfl_xor(32).
__device__ __forceinline__ float4 conv_accum(const float* __restrict__ CT,
                                             const float* __restrict__ xp,
                                             int og, int sh) {
  float4 a = make_float4(0.f, 0.f, 0.f, 0.f);
  const float4* wp = (const float4*)CT + og;
#pragma unroll 8
  for (int j = 0; j < 64; ++j) {
    int k = (j << 1) + sh;
    float f = xp[k];
    float4 wv = wp[(size_t)k * 32];
    a.x = fmaf(f, wv.x, a.x);
    a.y = fmaf(f, wv.y, a.y);
    a.z = fmaf(f, wv.z, a.z);
    a.w = fmaf(f, wv.w, a.w);
  }
  a.x += __shfl_xor(a.x, 32);
  a.y += __shfl_xor(a.y, 32);
  a.z += __shfl_xor(a.z, 32);
  a.w += __shfl_xor(a.w, 32);
  return a;
}

template<bool TR>
__global__ __launch_bounds__(256, 4) void proposal_kernel(
    const float* __restrict__ vote_xyz, const float* __restrict__ vote_feat,
    const float* __restrict__ wsf, const float* __restrict__ msa,
    const float* __restrict__ s0, const float* __restrict__ b0,
    const float* __restrict__ s1, const float* __restrict__ b1,
    const float* __restrict__ s2, const float* __restrict__ b2,
    const float* __restrict__ c1b, const float* __restrict__ bn1s, const float* __restrict__ bn1b,
    const float* __restrict__ c2b, const float* __restrict__ bn2s, const float* __restrict__ bn2b,
    const float* __restrict__ c3b,
    float* __restrict__ out) {
  __shared__ __align__(16) float Xbuf[4 * XSTR];  // per-wave 131-row chunk / H buffer / epilogue scratch
  __shared__ int sel_s[4][NS];
  __shared__ float sc_s[4][3], sh_s[4][3];
  __shared__ int scls_s[4];

  const int t = threadIdx.x;
  const int w = t >> 6, l = t & 63;
  const int b = blockIdx.x >> 6;
  const int pp = ((blockIdx.x & 63) << 2) + w;
  const int sh = l >> 5, og = l & 31;
  float* Xw = Xbuf + w * XSTR;
  // epilogue overlays into Xw (dead after MLP; wave-private in-order DS)
  float* feat_p = Xw;          // 128
  float* n1_p   = Xw + 128;    // 128
  float* n2_p   = Xw + 256;    // 128
  float* ntv_p  = Xw + 384;    // 119 (pad to 120)

  const float* nx = wsf + WS_NEWXYZ + ((size_t)b * NPROPN + pp) * 3;
  const float cx = nx[0], cy = nx[1], cz = nx[2];
  const float* px = vote_xyz + (size_t)b * KK * 3;
  const float RR = 0.09000000357627869f;  // f32(0.3f*0.3f)

  // ---- ball query: first <=16 in-radius indices, ascending; batched loads ----
  int total = 0;
  {
    for (int j0 = 0; j0 < 32 && total < NS; j0 += 8) {
      float dq[8];
#pragma unroll
      for (int jj = 0; jj < 8; ++jj) {
        int i = ((j0 + jj) << 6) + l;
        float dx = __fsub_rn(px[i * 3 + 0], cx);
        float dy = __fsub_rn(px[i * 3 + 1], cy);
        float dz = __fsub_rn(px[i * 3 + 2], cz);
        dq[jj] = __fadd_rn(__fadd_rn(__fmul_rn(dx, dx), __fmul_rn(dy, dy)), __fmul_rn(dz, dz));
      }
#pragma unroll
      for (int jj = 0; jj < 8; ++jj) {
        bool in = (dq[jj] <= RR);
        unsigned long long bal = __ballot(in);
        if (in) {
          int pos = total + __popcll(bal & ((1ull << l) - 1ull));
          if (pos < NS) sel_s[w][pos] = ((j0 + jj) << 6) + l;
        }
        total += __popcll(bal);
      }
    }
    if (l == 0 && total < NS) {
      int first = (total > 0) ? sel_s[w][0] : 0;
      for (int i = total; i < NS; ++i) sel_s[w][i] = first;
    }
    __builtin_amdgcn_wave_barrier();
  }

  // ---- gather chunk0 (global rows 0..130) + prefetch chunk1 into regs ----
  float4 pf[8];
  {
    const int s = l >> 2, q = l & 3;
    const int idx = sel_s[w][s];
    const int s4 = s >> 2, se = s & 3;
    if (q < 3) {
      float pv = px[idx * 3 + q];
      float cv = (q == 0) ? cx : ((q == 1) ? cy : cz);
      Xw[xadr(q, s4) + se] = __fdiv_rn(__fsub_rn(pv, cv), 0.3f);
    }
    if constexpr (TR) {
      const float* fr = wsf + WS_FEATT + ((size_t)b * KK + idx) * CSEED;
#pragma unroll
      for (int m = 0; m < 8; ++m) {
        int c = (m << 4) + (q << 2);
        float4 v = *(const float4*)(fr + c);
        Xw[xadr(3 + c + 0, s4) + se] = v.x;
        Xw[xadr(3 + c + 1, s4) + se] = v.y;
        Xw[xadr(3 + c + 2, s4) + se] = v.z;
        Xw[xadr(3 + c + 3, s4) + se] = v.w;
      }
#pragma unroll
      for (int m = 0; m < 8; ++m) pf[m] = *(const float4*)(fr + 128 + (m << 4) + (q << 2));
    } else {
      const float* fb = vote_feat + (size_t)b * CSEED * KK + idx;
#pragma unroll
      for (int m = 0; m < 8; ++m) {
        int c = (m << 4) + (q << 2);
        Xw[xadr(3 + c + 0, s4) + se] = fb[(size_t)(c + 0) * KK];
        Xw[xadr(3 + c + 1, s4) + se] = fb[(size_t)(c + 1) * KK];
        Xw[xadr(3 + c + 2, s4) + se] = fb[(size_t)(c + 2) * KK];
        Xw[xadr(3 + c + 3, s4) + se] = fb[(size_t)(c + 3) * KK];
      }
#pragma unroll
      for (int m = 0; m < 8; ++m) {
        int c = 128 + (m << 4) + (q << 2);
        pf[m].x = fb[(size_t)(c + 0) * KK];
        pf[m].y = fb[(size_t)(c + 1) * KK];
        pf[m].z = fb[(size_t)(c + 2) * KK];
        pf[m].w = fb[(size_t)(c + 3) * KK];
      }
    }
    __builtin_amdgcn_wave_barrier();
  }

  auto write_chunk1 = [&]() {
    const int s = l >> 2, q = l & 3;
    const int s4 = s >> 2, se = s & 3;
#pragma unroll
    for (int m = 0; m < 8; ++m) {
      int c = (m << 4) + (q << 2);
      Xw[xadr(c + 0, s4) + se] = pf[m].x;
      Xw[xadr(c + 1, s4) + se] = pf[m].y;
      Xw[xadr(c + 2, s4) + se] = pf[m].z;
      Xw[xadr(c + 3, s4) + se] = pf[m].w;
    }
  };

  float4 acc[8];
#pragma unroll
  for (int i = 0; i < 8; ++i) acc[i] = make_float4(0.f, 0.f, 0.f, 0.f);

  if (total <= 8) {
    // ======== FAST path: only samples 0..7 matter (pads duplicate sel[0]) ========
    mlp_accum_pair(wsf + WS_W0T, og, sh, Xw, 131, acc);
    __builtin_amdgcn_wave_barrier();
    write_chunk1();
    __builtin_amdgcn_wave_barrier();
    mlp_accum_pair(wsf + WS_W0T + 131 * 128, og, sh, Xw, 128, acc);
    pair_combine(acc);
    mlp_storeh(s0, b0, og, sh, Xw, acc);
    __builtin_amdgcn_wave_barrier();
#pragma unroll
    for (int i = 0; i < 8; ++i) acc[i] = make_float4(0.f, 0.f, 0.f, 0.f);
    mlp_accum_pair(wsf + WS_W1T, og, sh, Xw, 128, acc);
    pair_combine(acc);
    mlp_storeh(s1, b1, og, sh, Xw, acc);
    __builtin_amdgcn_wave_barrier();
#pragma unroll
    for (int i = 0; i < 8; ++i) acc[i] = make_float4(0.f, 0.f, 0.f, 0.f);
    mlp_accum_pair(wsf + WS_W2T, og, sh, Xw, 128, acc);
    pair_combine(acc);
  } else {
    // ======== SLOW path: exact R11 code ========
    mlp_accum(wsf + WS_W0T, og, sh, Xw, 131, acc);
    __builtin_amdgcn_wave_barrier();
    write_chunk1();
    __builtin_amdgcn_wave_barrier();
    mlp_accum(wsf + WS_W0T + 131 * 128, og, sh, Xw, 128, acc);
    mlp_storeh(s0, b0, og, sh, Xw, acc);
    __builtin_amdgcn_wave_barrier();
#pragma unroll
    for (int i = 0; i < 8; ++i) acc[i] = make_float4(0.f, 0.f, 0.f, 0.f);
    mlp_accum(wsf + WS_W1T, og, sh, Xw, 128, acc);
    mlp_storeh(s1, b1, og, sh, Xw, acc);
    __builtin_amdgcn_wave_barrier();
#pragma unroll
    for (int i = 0; i < 8; ++i) acc[i] = make_float4(0.f, 0.f, 0.f, 0.f);
    mlp_accum(wsf + WS_W2T, og, sh, Xw, 128, acc);
  }

  // ---- epilogue: scale/bias/relu + maxpool (shared; fast path acc is combined) ----
  float mr[4];
  {
    float4 s4v = *(const float4*)(s2 + (og << 2));
    float4 b4v = *(const float4*)(b2 + (og << 2));
#pragma unroll
    for (int r = 0; r < 4; ++r) {
      float ss = fget(s4v, r), bv = fget(b4v, r);
      float m = 0.f;  // relu floor
#pragma unroll
      for (int i = 0; i < 8; ++i) m = fmaxf(m, fmaf(fget(acc[i], r), ss, bv));
      mr[r] = fmaxf(m, __shfl_xor(m, 32));
    }
  }
  __builtin_amdgcn_wave_barrier();  // all Xw reads (L2) done before overlay writes
  if (sh == 0) *(float4*)(feat_p + (og << 2)) = make_float4(mr[0], mr[1], mr[2], mr[3]);
  __builtin_amdgcn_wave_barrier();

  // ---- obj_surface_feature tile x6 ----
  {
    float* o11 = out + O11 + (size_t)b * CMLP * 1536;
#pragma unroll
    for (int r = 0; r < 4; ++r) {
      size_t rowb = (size_t)((og << 2) + r) * 1536 + pp;
#pragma unroll
      for (int rr2 = 0; rr2 < 3; ++rr2) {
        int rr = sh * 3 + rr2;
        o11[rowb + rr * 256] = mr[r];
      }
    }
  }

  // ---- conv chain: split-k float4 loads, unroll 8, shfl combine ----
  {
    float4 a = conv_accum(wsf + WS_C1T, feat_p, og, sh);
    int o = og << 2;
    float4 res;
    res.x = fmaf(a.x + c1b[o + 0], bn1s[o + 0], bn1b[o + 0]); res.x = res.x > 0.f ? res.x : 0.f;
    res.y = fmaf(a.y + c1b[o + 1], bn1s[o + 1], bn1b[o + 1]); res.y = res.y > 0.f ? res.y : 0.f;
    res.z = fmaf(a.z + c1b[o + 2], bn1s[o + 2], bn1b[o + 2]); res.z = res.z > 0.f ? res.z : 0.f;
    res.w = fmaf(a.w + c1b[o + 3], bn1s[o + 3], bn1b[o + 3]); res.w = res.w > 0.f ? res.w : 0.f;
    if (sh == 0) *(float4*)(n1_p + o) = res;
    __builtin_amdgcn_wave_barrier();
  }
  {
    float4 a = conv_accum(wsf + WS_C2T, n1_p, og, sh);
    int o = og << 2;
    float4 res;
    res.x = fmaf(a.x + c2b[o + 0], bn2s[o + 0], bn2b[o + 0]); res.x = res.x > 0.f ? res.x : 0.f;
    res.y = fmaf(a.y + c2b[o + 1], bn2s[o + 1], bn2b[o + 1]); res.y = res.y > 0.f ? res.y : 0.f;
    res.z = fmaf(a.z + c2b[o + 2], bn2s[o + 2], bn2b[o + 2]); res.z = res.z > 0.f ? res.z : 0.f;
    res.w = fmaf(a.w + c2b[o + 3], bn2s[o + 3], bn2b[o + 3]); res.w = res.w > 0.f ? res.w : 0.f;
    if (sh == 0) *(float4*)(n2_p + o) = res;
    __builtin_amdgcn_wave_barrier();
  }
  {
    float4 a = conv_accum(wsf + WS_C3T, n2_p, og, sh);
    int o = og << 2;
    float4 res;
    res.x = a.x + ((o + 0 < OUTCH) ? c3b[o + 0] : 0.f);
    res.y = a.y + ((o + 1 < OUTCH) ? c3b[o + 1] : 0.f);
    res.z = a.z + ((o + 2 < OUTCH) ? c3b[o + 2] : 0.f);
    res.w = a.w + ((o + 3 < OUTCH) ? c3b[o + 3] : 0.f);
    if (sh == 0 && o < 120) *(float4*)(ntv_p + o) = res;
    __builtin_amdgcn_wave_barrier();
  }

  // ---- heads (wave-private) ----
  {
    const size_t bp = (size_t)b * NPROPN + pp;
    if (l < 2) out[O0 + bp * 2 + l] = ntv_p[l];
    if (l < 3) {
      float cv = ((l == 0) ? cx : ((l == 1) ? cy : cz)) + ntv_p[2 + l];
      sc_s[w][l] = cv;
      out[O1 + bp * 3 + l] = cv;
    }
    if (l < 12) {
      out[O2 + bp * 12 + l] = ntv_p[5 + l];
      out[O3 + bp * 12 + l] = ntv_p[17 + l] * 0.2617993877991494f;
    }
    if (l < 18) {
      out[O4 + bp * 18 + l] = ntv_p[29 + l];
      out[O6 + bp * 18 + l] = ntv_p[101 + l];
    }
    if (l < 54) out[O5 + bp * 54 + l] = ntv_p[47 + l] * msa[l];
    if (l == 0) {
      float bvv = ntv_p[29]; int bii = 0;
      for (int i2 = 1; i2 < 18; ++i2)
        if (ntv_p[29 + i2] > bvv) { bvv = ntv_p[29 + i2]; bii = i2; }
      scls_s[w] = bii;
    }
    __builtin_amdgcn_wave_barrier();
    if (l < 3) {
      int cls = scls_s[w];
      float m = msa[cls * 3 + l];
      sh_s[w][l] = fmaf(ntv_p[47 + cls * 3 + l], m, m) * 0.5f;
    }
    __builtin_amdgcn_wave_barrier();
    if (l < 18) {
      const int r = l / 3, j2 = l % 3;
      const int axis[6] = {2, 2, 1, 1, 0, 0};
      float v = sc_s[w][j2];
      if (j2 == axis[r]) v = (r & 1) ? (v - sh_s[w][j2]) : (v + sh_s[w][j2]);
      out[O10 + (size_t)b * 4608 + (size_t)(r * 256 + pp) * 3 + j2] = v;
    }
  }
}

extern "C" void kernel_launch(void* const* d_in, const int* in_sizes, int n_in,
                              void* d_out, int out_size, void* d_ws, size_t ws_size,
                              hipStream_t stream) {
  (void)in_sizes; (void)n_in; (void)out_size;
  const float* vote_xyz = (const float*)d_in[0];
  const float* vote_feat = (const float*)d_in[1];
  const float* pz   = (const float*)d_in[2];
  const float* cz   = (const float*)d_in[3];
  const float* az   = (const float*)d_in[4];
  const float* pxy  = (const float*)d_in[5];
  const float* cxy  = (const float*)d_in[6];
  const float* axy  = (const float*)d_in[7];
  const float* pl   = (const float*)d_in[8];
  const float* cl   = (const float*)d_in[9];
  const float* msa  = (const float*)d_in[11];
  const float* w0   = (const float*)d_in[12];
  const float* s0   = (const float*)d_in[13];
  const float* b0   = (const float*)d_in[14];
  const float* w1   = (const float*)d_in[15];
  const float* s1   = (const float*)d_in[16];
  const float* b1   = (const float*)d_in[17];
  const float* w2   = (const float*)d_in[18];
  const float* s2   = (const float*)d_in[19];
  const float* b2   = (const float*)d_in[20];
  const float* c1w  = (const float*)d_in[21];
  const float* c1b  = (const float*)d_in[22];
  const float* bn1s = (const float*)d_in[23];
  const float* bn1b = (const float*)d_in[24];
  const float* c2w  = (const float*)d_in[25];
  const float* c2b  = (const float*)d_in[26];
  const float* bn2s = (const float*)d_in[27];
  const float* bn2b = (const float*)d_in[28];
  const float* c3w  = (const float*)d_in[29];
  const float* c3b  = (const float*)d_in[30];
  float* out = (float*)d_out;
  float* wsf = (float*)d_ws;

  if (ws_size >= WS_NEED_BYTES) {
    hipLaunchKernelGGL((prep_kernel<true>), dim3(16 + 1024 + 450 + 192 + 4096), dim3(256), 0, stream,
                       vote_xyz, vote_feat, w0, w1, w2, c1w, c2w, c3w,
                       pz, cz, pxy, cxy, pl, cl, az, axy, wsf, out);
    hipLaunchKernelGGL((proposal_kernel<true>), dim3(BB * NPROPN / 4), dim3(256), 0, stream,
                       vote_xyz, vote_feat, wsf, msa,
                       s0, b0, s1, b1, s2, b2,
                       c1b, bn1s, bn1b, c2b, bn2s, bn2b, c3b, out);
  } else {
    hipLaunchKernelGGL((prep_kernel<false>), dim3(16 + 450 + 192 + 4096), dim3(256), 0, stream,
                       vote_xyz, vote_feat, w0, w1, w2, c1w, c2w, c3w,
                       pz, cz, pxy, cxy, pl, cl, az, axy, wsf, out);
    hipLaunchKernelGGL((proposal_kernel<false>), dim3(BB * NPROPN / 4), dim3(256), 0, stream,
                       vote_xyz, vote_feat, wsf, msa,
                       s0, b0, s1, b1, s2, b2,
                       c1b, bn1s, bn1b, c2b, bn2s, bn2b, c3b, out);
  }
}